// Round 11
// baseline (986.204 us; speedup 1.0000x reference)
//
#include <hip/hip_runtime.h>

#define NB 16
#define NT 128
#define NC 64
#define NU 128
#define UNFOLDS 6
#define LTC_EPS 1e-8f
#define LOG2E 1.44269504088896340736f
#define LN2   0.69314718055994530942f

typedef float f32x2 __attribute__((ext_vector_type(2)));

__device__ __forceinline__ float fast_softplus(float x) {
    return LN2 * __builtin_amdgcn_logf(1.0f + __builtin_amdgcn_exp2f(x * LOG2E));
}

template<int CTRL>
__device__ __forceinline__ float qperm(float x) {
    return __int_as_float(__builtin_amdgcn_update_dpp(
        0, __float_as_int(x), CTRL, 0xF, 0xF, true));
}
// sum over the 8 lanes of a k-group; all stages DPP (VALU pipe, no LDS)
__device__ __forceinline__ float sum8(float x) {
    x += qperm<0xB1>(x);    // quad_perm xor-1
    x += qperm<0x4E>(x);    // quad_perm xor-2
    x += qperm<0x141>(x);   // row_half_mirror (verified r7)
    return x;
}

// ---------------- Kernel 1: sensory precompute (fully parallel) ----------------
__global__ __launch_bounds__(128)
void ltc_sens_kernel(const float* __restrict__ x,
                     const float* __restrict__ ssigma,
                     const float* __restrict__ smu,
                     const float* __restrict__ sw,
                     const float* __restrict__ serev,
                     const float* __restrict__ iw,
                     const float* __restrict__ ib,
                     float2* __restrict__ sens)
{
    __shared__ float xt[NC];
    const int blk = blockIdx.x;
    const int b = blk >> 7;
    const int t = blk & (NT - 1);
    const int j = threadIdx.x;
    if (j < NC) xt[j] = fmaf(x[(b * NT + t) * NC + j], iw[j], ib[j]);
    __syncthreads();

    float n0 = 0.f, n1 = 0.f, d0 = 0.f, d1 = 0.f;
#pragma unroll 8
    for (int c = 0; c < NC; ++c) {
        const int idx = c * NU + j;
        float sg = ssigma[idx];
        float m  = smu[idx];
        float wp = fast_softplus(sw[idx]);
        float er = serev[idx];
        float tt = (m - xt[c]) * (sg * LOG2E);
        float e  = __builtin_amdgcn_exp2f(tt);
        float r  = __builtin_amdgcn_rcpf(1.0f + e);
        float wr = wp * r;
        if (c & 1) { n1 = fmaf(wr, er, n1); d1 += wr; }
        else       { n0 = fmaf(wr, er, n0); d0 += wr; }
    }
    sens[(b * NT + t) * NU + j] = make_float2(n0 + n1, d0 + d1);
}

// ---------------- Kernel 2: sequential scan, 8 lanes per post-unit ----------------
__global__ __launch_bounds__(1024, 4)
void ltc_seq_kernel(const float* __restrict__ h0,
                    const float* __restrict__ gleak,
                    const float* __restrict__ vleak,
                    const float* __restrict__ cm,
                    const float* __restrict__ sigma,
                    const float* __restrict__ mu,
                    const float* __restrict__ w,
                    const float* __restrict__ erev,
                    const float* __restrict__ ow,
                    const float* __restrict__ ob,
                    const float2* __restrict__ sens,
                    float* __restrict__ out)
{
    __shared__ __align__(16) float v_lds[2][NU];

    const int tid = threadIdx.x;
    const int b   = blockIdx.x;
    const int j   = tid >> 3;   // post-unit (128)
    const int k   = tid & 7;    // pre-chunk (8 x 16 rows)

    // b128 v reads: chunk m reads pre-rows i0 = k*16 + rot*4 + {0..3},
    // rot = (m + (k>>1)) & 3  (verified conflict-free r9).
    f32x2 rA2[8], rB2[8], rW2[8], aW2[8];
#pragma unroll
    for (int m = 0; m < 4; ++m) {
        const int rot = (m + (k >> 1)) & 3;
#pragma unroll
        for (int h = 0; h < 2; ++h) {
            const int c   = 2 * m + h;                 // param slot
            const int i0  = (k << 4) + (rot << 2) + 2 * h;
            const int id0 = i0 * NU + j;
            const int id1 = id0 + NU;
            const float sg0 = sigma[id0], sg1 = sigma[id1];
            const float m0  = mu[id0],    m1  = mu[id1];
            const float wp0 = fast_softplus(w[id0]), wp1 = fast_softplus(w[id1]);
            const float er0 = erev[id0],  er1 = erev[id1];
            f32x2 a;  a.x = -sg0 * LOG2E;  a.y = -sg1 * LOG2E;
            f32x2 bb; bb.x = -a.x * m0;    bb.y = -a.y * m1;
            f32x2 ww; ww.x = wp0 * er0;    ww.y = wp1 * er1;
            f32x2 aw; aw.x = wp0;          aw.y = wp1;     // |w| (er = ±1)
            rA2[c] = a; rB2[c] = bb; rW2[c] = ww; aW2[c] = aw;
        }
    }

    const float cmt    = 6.0f * fast_softplus(cm[j]);
    const float gl     = fast_softplus(gleak[j]);
    const float glv    = gl * vleak[j];
    const float cmt_gl = cmt + gl + LTC_EPS;
    const float owj    = ow[j];
    const float obj    = ob[j];
    float vj = h0[b * NU + j];
    if (k == 0) v_lds[0][j] = vj;
    __syncthreads();

    int p = 0;
    float2 s_cur = sens[b * NT * NU + j];

    for (int t = 0; t < NT; ++t) {
        // register pin (zero instructions; blocks reload/remat schemes)
#pragma unroll
        for (int q = 0; q < 8; ++q) {
            asm volatile("" : "+v"(rA2[q]), "+v"(rB2[q]), "+v"(rW2[q]), "+v"(aW2[q]));
        }

        const float nb = 0.125f * (s_cur.x + glv);
        const float db = 0.125f * (s_cur.y + cmt_gl);
        const int tn = (t + 1 < NT) ? (t + 1) : t;
        const float2 s_next = sens[(b * NT + tn) * NU + j];   // prefetch

#pragma unroll
        for (int u = 0; u < UNFOLDS; ++u) {
            f32x2 n2a = {nb, 0.f}, n2b = {0.f, 0.f};
            f32x2 d2a = {db, 0.f}, d2b = {0.f, 0.f};
#pragma unroll
            for (int h4 = 0; h4 < 2; ++h4) {       // pairs of slots -> quad-rcp
                const int mA = 2 * h4, mB = 2 * h4 + 1;
                const int rotA = (mA + (k >> 1)) & 3;
                const int rotB = (mB + (k >> 1)) & 3;
                const float4 vvA = *(const float4*)&v_lds[p][(k << 4) + (rotA << 2)];
                const float4 vvB = *(const float4*)&v_lds[p][(k << 4) + (rotB << 2)];
                const f32x2 vA0 = {vvA.x, vvA.y};
                const f32x2 vA1 = {vvA.z, vvA.w};
                const f32x2 vB0 = {vvB.x, vvB.y};
                const f32x2 vB1 = {vvB.z, vvB.w};
                const f32x2 tA0 = rA2[2 * mA] * vA0 + rB2[2 * mA];
                const f32x2 tA1 = rA2[2 * mA + 1] * vA1 + rB2[2 * mA + 1];
                const f32x2 tB0 = rA2[2 * mB] * vB0 + rB2[2 * mB];
                const f32x2 tB1 = rA2[2 * mB + 1] * vB1 + rB2[2 * mB + 1];

                // ---- software exp2 (packed poly + ldexp), |t| <= 21 ----
                // 2^t = 2^n * 2^f, n = rint(t), f in [-1/2,1/2];
                // 2^f = Taylor deg-4 (rel err ~4e-5, 25x below budget)
#define SOFT_EXP2(tt, ee)                                                   \
                {                                                           \
                    const float nn0 = __builtin_rintf((tt).x);              \
                    const float nn1 = __builtin_rintf((tt).y);              \
                    f32x2 nf; nf.x = nn0; nf.y = nn1;                       \
                    const f32x2 ff = (tt) - nf;                             \
                    const f32x2 c4v = {0.009618129f, 0.009618129f};         \
                    const f32x2 c3v = {0.055504109f, 0.055504109f};         \
                    const f32x2 c2v = {0.240226507f, 0.240226507f};         \
                    const f32x2 c1v = {0.693147181f, 0.693147181f};         \
                    const f32x2 c0v = {1.0f, 1.0f};                         \
                    f32x2 gg = c4v * ff + c3v;                              \
                    gg = gg * ff + c2v;                                     \
                    gg = gg * ff + c1v;                                     \
                    gg = gg * ff + c0v;                                     \
                    (ee).x = __builtin_amdgcn_ldexpf(gg.x, (int)nn0);       \
                    (ee).y = __builtin_amdgcn_ldexpf(gg.y, (int)nn1);       \
                }
                f32x2 eA0, eA1, eB0, eB1;
                SOFT_EXP2(tA0, eA0)
                SOFT_EXP2(tA1, eA1)
                SOFT_EXP2(tB0, eB0)
                SOFT_EXP2(tB1, eB1)
#undef SOFT_EXP2

                const f32x2 one = {1.0f, 1.0f};
                const f32x2 uA0 = eA0 + one;
                const f32x2 uA1 = eA1 + one;
                const f32x2 uB0 = eB0 + one;
                const f32x2 uB1 = eB1 + one;

                // quad-rcp per slot-pair, swap-free recovery (verified r9)
                {
                    const f32x2 p2 = uA0 * uA1;
                    const float P  = p2.x * p2.y;
                    const float R  = __builtin_amdgcn_rcpf(P);
                    f32x2 rr; rr.x = R * p2.y; rr.y = R * p2.x;
                    const f32x2 r0 = rr * uA1;
                    const f32x2 r1 = rr * uA0;
                    n2a = rW2[2 * mA] * r0 + n2a;
                    n2b = rW2[2 * mA + 1] * r1 + n2b;
                    d2a = aW2[2 * mA] * r0 + d2a;
                    d2b = aW2[2 * mA + 1] * r1 + d2b;
                }
                {
                    const f32x2 p2 = uB0 * uB1;
                    const float P  = p2.x * p2.y;
                    const float R  = __builtin_amdgcn_rcpf(P);
                    f32x2 rr; rr.x = R * p2.y; rr.y = R * p2.x;
                    const f32x2 r0 = rr * uB1;
                    const f32x2 r1 = rr * uB0;
                    n2a = rW2[2 * mB] * r0 + n2a;
                    n2b = rW2[2 * mB + 1] * r1 + n2b;
                    d2a = aW2[2 * mB] * r0 + d2a;
                    d2b = aW2[2 * mB + 1] * r1 + d2b;
                }
            }
            const f32x2 n2 = n2a + n2b;
            const f32x2 d2 = d2a + d2b;
            const float wn = sum8(n2.x + n2.y);   // includes snum+glv
            const float wd = sum8(d2.x + d2.y);   // includes sden+cmt+gl+eps
            const float numf = fmaf(cmt, vj, wn);
            vj = numf * __builtin_amdgcn_rcpf(wd);   // redundant in 8 lanes
            if (k == 0) v_lds[p ^ 1][j] = vj;
            __syncthreads();                         // one barrier per unfold
            p ^= 1;
        }

        if (k == 0) out[(b * NT + t) * NU + j] = fmaf(vj, owj, obj);
        s_cur = s_next;
    }
    if (k == 0) out[NB * NT * NU + b * NU + j] = vj;    // h_final
}

extern "C" void kernel_launch(void* const* d_in, const int* in_sizes, int n_in,
                              void* d_out, int out_size, void* d_ws, size_t ws_size,
                              hipStream_t stream) {
    const float* x      = (const float*)d_in[0];
    const float* h0     = (const float*)d_in[1];
    const float* gleak  = (const float*)d_in[2];
    const float* vleak  = (const float*)d_in[3];
    const float* cm     = (const float*)d_in[4];
    const float* sigma  = (const float*)d_in[5];
    const float* mu     = (const float*)d_in[6];
    const float* w      = (const float*)d_in[7];
    const float* erev   = (const float*)d_in[8];
    const float* ssig   = (const float*)d_in[9];
    const float* smu    = (const float*)d_in[10];
    const float* sw     = (const float*)d_in[11];
    const float* serev  = (const float*)d_in[12];
    const float* iw     = (const float*)d_in[13];
    const float* ibv    = (const float*)d_in[14];
    const float* ow     = (const float*)d_in[15];
    const float* ob     = (const float*)d_in[16];
    float* out = (float*)d_out;

    float2* sens = (float2*)d_ws;   // 2 MB scratch
    ltc_sens_kernel<<<NB * NT, 128, 0, stream>>>(x, ssig, smu, sw, serev, iw, ibv, sens);
    ltc_seq_kernel<<<NB, 1024, 0, stream>>>(h0, gleak, vleak, cm, sigma, mu, w, erev,
                                            ow, ob, (const float2*)sens, out);
}

// Round 12
// 705.168 us; speedup vs baseline: 1.3985x; 1.3985x over previous
//
#include <hip/hip_runtime.h>

#define NB 16
#define NT 128
#define NC 64
#define NU 128
#define UNFOLDS 6
#define LTC_EPS 1e-8f
#define LOG2E 1.44269504088896340736f
#define LN2   0.69314718055994530942f

typedef float f32x2 __attribute__((ext_vector_type(2)));

__device__ __forceinline__ float fast_softplus(float x) {
    return LN2 * __builtin_amdgcn_logf(1.0f + __builtin_amdgcn_exp2f(x * LOG2E));
}

template<int CTRL>
__device__ __forceinline__ float qperm(float x) {
    return __int_as_float(__builtin_amdgcn_update_dpp(
        0, __float_as_int(x), CTRL, 0xF, 0xF, true));
}
// sum over the 8 lanes of a k-group; all stages DPP (VALU pipe, no LDS)
__device__ __forceinline__ float sum8(float x) {
    x += qperm<0xB1>(x);    // quad_perm xor-1
    x += qperm<0x4E>(x);    // quad_perm xor-2
    x += qperm<0x141>(x);   // row_half_mirror (verified r7)
    return x;
}

// ---------------- Kernel 1: sensory precompute (fully parallel) ----------------
__global__ __launch_bounds__(128)
void ltc_sens_kernel(const float* __restrict__ x,
                     const float* __restrict__ ssigma,
                     const float* __restrict__ smu,
                     const float* __restrict__ sw,
                     const float* __restrict__ serev,
                     const float* __restrict__ iw,
                     const float* __restrict__ ib,
                     float2* __restrict__ sens)
{
    __shared__ float xt[NC];
    const int blk = blockIdx.x;
    const int b = blk >> 7;
    const int t = blk & (NT - 1);
    const int j = threadIdx.x;
    if (j < NC) xt[j] = fmaf(x[(b * NT + t) * NC + j], iw[j], ib[j]);
    __syncthreads();

    float n0 = 0.f, n1 = 0.f, d0 = 0.f, d1 = 0.f;
#pragma unroll 8
    for (int c = 0; c < NC; ++c) {
        const int idx = c * NU + j;
        float sg = ssigma[idx];
        float m  = smu[idx];
        float wp = fast_softplus(sw[idx]);
        float er = serev[idx];
        float tt = (m - xt[c]) * (sg * LOG2E);
        float e  = __builtin_amdgcn_exp2f(tt);
        float r  = __builtin_amdgcn_rcpf(1.0f + e);
        float wr = wp * r;
        if (c & 1) { n1 = fmaf(wr, er, n1); d1 += wr; }
        else       { n0 = fmaf(wr, er, n0); d0 += wr; }
    }
    sens[(b * NT + t) * NU + j] = make_float2(n0 + n1, d0 + d1);
}

// ---------------- Kernel 2: sequential scan, 8 lanes per post-unit ----------------
__global__ __launch_bounds__(1024, 4)
void ltc_seq_kernel(const float* __restrict__ h0,
                    const float* __restrict__ gleak,
                    const float* __restrict__ vleak,
                    const float* __restrict__ cm,
                    const float* __restrict__ sigma,
                    const float* __restrict__ mu,
                    const float* __restrict__ w,
                    const float* __restrict__ erev,
                    const float* __restrict__ ow,
                    const float* __restrict__ ob,
                    const float2* __restrict__ sens,
                    float* __restrict__ out)
{
    __shared__ __align__(16) float v_lds[2][NU];

    const int tid = threadIdx.x;
    const int b   = blockIdx.x;
    const int j   = tid >> 3;   // post-unit (128)
    const int k   = tid & 7;    // pre-chunk (8 x 16 rows)

    // b128 v reads: chunk m reads pre-rows i0 = k*16 + rot*4 + {0..3},
    // rot = (m + (k>>1)) & 3  (verified conflict-free r9).
    f32x2 rA2[8], rB2[8], rW2[8], aW2[8];
#pragma unroll
    for (int m = 0; m < 4; ++m) {
        const int rot = (m + (k >> 1)) & 3;
#pragma unroll
        for (int h = 0; h < 2; ++h) {
            const int c   = 2 * m + h;                 // param slot
            const int i0  = (k << 4) + (rot << 2) + 2 * h;
            const int id0 = i0 * NU + j;
            const int id1 = id0 + NU;
            const float sg0 = sigma[id0], sg1 = sigma[id1];
            const float m0  = mu[id0],    m1  = mu[id1];
            const float wp0 = fast_softplus(w[id0]), wp1 = fast_softplus(w[id1]);
            const float er0 = erev[id0],  er1 = erev[id1];
            f32x2 a;  a.x = -sg0 * LOG2E;  a.y = -sg1 * LOG2E;
            f32x2 bb; bb.x = -a.x * m0;    bb.y = -a.y * m1;
            f32x2 ww; ww.x = wp0 * er0;    ww.y = wp1 * er1;
            f32x2 aw; aw.x = wp0;          aw.y = wp1;     // |w| (er = ±1)
            rA2[c] = a; rB2[c] = bb; rW2[c] = ww; aW2[c] = aw;
        }
    }

    const float cmt    = 6.0f * fast_softplus(cm[j]);
    const float gl     = fast_softplus(gleak[j]);
    const float glv    = gl * vleak[j];
    const float cmt_gl = cmt + gl + LTC_EPS;
    const float owj    = ow[j];
    const float obj    = ob[j];
    float vj = h0[b * NU + j];
    if (k == 0) v_lds[0][j] = vj;
    __syncthreads();

    int p = 0;
    float2 s_cur = sens[b * NT * NU + j];

    for (int t = 0; t < NT; ++t) {
        // register pin (zero instructions; blocks reload/remat schemes)
#pragma unroll
        for (int q = 0; q < 8; ++q) {
            asm volatile("" : "+v"(rA2[q]), "+v"(rB2[q]), "+v"(rW2[q]), "+v"(aW2[q]));
        }

        const float nb = 0.125f * (s_cur.x + glv);
        const float db = 0.125f * (s_cur.y + cmt_gl);
        const int tn = (t + 1 < NT) ? (t + 1) : t;
        const float2 s_next = sens[(b * NT + tn) * NU + j];   // prefetch

        const int kk = k >> 1;

#pragma unroll
        for (int u = 0; u < UNFOLDS; ++u) {
            f32x2 n2a = {nb, 0.f}, n2b = {0.f, 0.f};
            f32x2 d2a = {db, 0.f}, d2b = {0.f, 0.f};

            // ---- 2-deep software pipeline over the 4 chunks ----
            // load/eval/exp2 of chunk m+1 is issued BEFORE recovery of
            // chunk m, so trans-pipe bursts overlap recovery VALU.
            // Named vars only (r10's regression was array-indexing movs).
#define LOADEVAL(m, t0, t1)                                                  \
            f32x2 t0, t1;                                                    \
            {                                                                \
                const int rot = ((m) + kk) & 3;                              \
                const float4 vv = *(const float4*)&v_lds[p][(k << 4) + (rot << 2)]; \
                const f32x2 vlo = {vv.x, vv.y};                              \
                const f32x2 vhi = {vv.z, vv.w};                              \
                t0 = rA2[2 * (m)] * vlo + rB2[2 * (m)];                      \
                t1 = rA2[2 * (m) + 1] * vhi + rB2[2 * (m) + 1];              \
            }
#define EXP2U(t0, t1, u0, u1)                                                \
            f32x2 u0, u1;                                                    \
            {                                                                \
                const f32x2 one = {1.0f, 1.0f};                              \
                f32x2 e0, e1;                                                \
                e0.x = __builtin_amdgcn_exp2f((t0).x);                       \
                e0.y = __builtin_amdgcn_exp2f((t0).y);                       \
                e1.x = __builtin_amdgcn_exp2f((t1).x);                       \
                e1.y = __builtin_amdgcn_exp2f((t1).y);                       \
                u0 = e0 + one;                                               \
                u1 = e1 + one;                                               \
            }
#define RECOV(m, u0, u1)                                                     \
            {                                                                \
                const f32x2 p2 = (u0) * (u1);                                \
                const float P  = p2.x * p2.y;                                \
                const float R  = __builtin_amdgcn_rcpf(P);                   \
                f32x2 rr; rr.x = R * p2.y; rr.y = R * p2.x;                  \
                const f32x2 r0 = rr * (u1);                                  \
                const f32x2 r1 = rr * (u0);                                  \
                n2a = rW2[2 * (m)] * r0 + n2a;                               \
                n2b = rW2[2 * (m) + 1] * r1 + n2b;                           \
                d2a = aW2[2 * (m)] * r0 + d2a;                               \
                d2b = aW2[2 * (m) + 1] * r1 + d2b;                           \
            }
            LOADEVAL(0, t00, t01)
            EXP2U(t00, t01, u00, u01)
            LOADEVAL(1, t10, t11)
            EXP2U(t10, t11, u10, u11)
            RECOV(0, u00, u01)
            LOADEVAL(2, t20, t21)
            EXP2U(t20, t21, u20, u21)
            RECOV(1, u10, u11)
            LOADEVAL(3, t30, t31)
            EXP2U(t30, t31, u30, u31)
            RECOV(2, u20, u21)
            RECOV(3, u30, u31)
#undef LOADEVAL
#undef EXP2U
#undef RECOV

            const f32x2 n2 = n2a + n2b;
            const f32x2 d2 = d2a + d2b;
            const float wn = sum8(n2.x + n2.y);   // includes snum+glv
            const float wd = sum8(d2.x + d2.y);   // includes sden+cmt+gl+eps
            const float numf = fmaf(cmt, vj, wn);
            vj = numf * __builtin_amdgcn_rcpf(wd);   // redundant in 8 lanes
            if (k == 0) v_lds[p ^ 1][j] = vj;
            __syncthreads();                         // one barrier per unfold
            p ^= 1;
        }

        if (k == 0) out[(b * NT + t) * NU + j] = fmaf(vj, owj, obj);
        s_cur = s_next;
    }
    if (k == 0) out[NB * NT * NU + b * NU + j] = vj;    // h_final
}

extern "C" void kernel_launch(void* const* d_in, const int* in_sizes, int n_in,
                              void* d_out, int out_size, void* d_ws, size_t ws_size,
                              hipStream_t stream) {
    const float* x      = (const float*)d_in[0];
    const float* h0     = (const float*)d_in[1];
    const float* gleak  = (const float*)d_in[2];
    const float* vleak  = (const float*)d_in[3];
    const float* cm     = (const float*)d_in[4];
    const float* sigma  = (const float*)d_in[5];
    const float* mu     = (const float*)d_in[6];
    const float* w      = (const float*)d_in[7];
    const float* erev   = (const float*)d_in[8];
    const float* ssig   = (const float*)d_in[9];
    const float* smu    = (const float*)d_in[10];
    const float* sw     = (const float*)d_in[11];
    const float* serev  = (const float*)d_in[12];
    const float* iw     = (const float*)d_in[13];
    const float* ibv    = (const float*)d_in[14];
    const float* ow     = (const float*)d_in[15];
    const float* ob     = (const float*)d_in[16];
    float* out = (float*)d_out;

    float2* sens = (float2*)d_ws;   // 2 MB scratch
    ltc_sens_kernel<<<NB * NT, 128, 0, stream>>>(x, ssig, smu, sw, serev, iw, ibv, sens);
    ltc_seq_kernel<<<NB, 1024, 0, stream>>>(h0, gleak, vleak, cm, sigma, mu, w, erev,
                                            ow, ob, (const float2*)sens, out);
}